// Round 1
// baseline (875.549 us; speedup 1.0000x reference)
//
#include <hip/hip_runtime.h>

// GraphTransformer fused kernel set for MI355X (gfx950).
// N=50000 nodes, E=800000 edges, IN=128, H=4, D=16, HD=64, ED=16.
//
// Pipeline:
//   K1 gemm_qkvs : q,k,v = x@W+b into ws; skip = x@Wskip+bskip into d_out (init for scatter)
//   memset denom = 0
//   K2 edge_a    : alpha = (q[dst]·(k[src]+e))/4 ; ex=exp(alpha) -> ws ; atomicAdd denom[dst,h]
//   K3 edge_b    : asm = ex/(denom[dst]+1e-16) -> d_out ; atomicAdd out[dst] += asm*(v[src]+e)
//   K4 copy_ei   : edge_index -> d_out as float
//
// Softmax computed WITHOUT max-subtraction: mathematically identical ratio,
// |alpha| <= ~10 so exp() is safe in fp32.

__global__ __launch_bounds__(128) void gemm_qkvs(
    const float* __restrict__ x,
    const float* __restrict__ Wq, const float* __restrict__ bq,
    const float* __restrict__ Wk, const float* __restrict__ bk,
    const float* __restrict__ Wv, const float* __restrict__ bv,
    const float* __restrict__ Wsk, const float* __restrict__ bsk,
    float* __restrict__ q, float* __restrict__ k, float* __restrict__ v,
    float* __restrict__ outskip, int N)
{
    __shared__ float Xl[64 * 128];  // 32 KiB: 64 nodes x 128 features
    const int tid  = threadIdx.x;
    const int base = blockIdx.x * 64;
    const int nvalid = min(64, N - base);

    // cooperative float4 stage of the x tile
    for (int i = tid; i < 64 * 32; i += 128) {
        int node = i >> 5;
        float4 val = make_float4(0.f, 0.f, 0.f, 0.f);
        if (node < nvalid)
            val = reinterpret_cast<const float4*>(x)[(size_t)(base + node) * 32 + (i & 31)];
        reinterpret_cast<float4*>(Xl)[i] = val;
    }
    __syncthreads();

    const int wave = tid >> 6;
    const int lane = tid & 63;
    const int c   = lane * 4;      // virtual col 0..255 over [q|k|v|skip]
    const int arr = c >> 6;
    const int cc  = c & 63;
    const float* W; const float* B; float* O;
    if (arr == 0)      { W = Wq;  B = bq;  O = q; }
    else if (arr == 1) { W = Wk;  B = bk;  O = k; }
    else if (arr == 2) { W = Wv;  B = bv;  O = v; }
    else               { W = Wsk; B = bsk; O = outskip; }

    float acc[32][4];
    #pragma unroll
    for (int n = 0; n < 32; n++) {
        acc[n][0] = 0.f; acc[n][1] = 0.f; acc[n][2] = 0.f; acc[n][3] = 0.f;
    }

    const float* Xw = Xl + wave * 32 * 128;

    for (int kk = 0; kk < 128; kk += 4) {
        float4 w0 = *reinterpret_cast<const float4*>(W + (kk + 0) * 64 + cc);
        float4 w1 = *reinterpret_cast<const float4*>(W + (kk + 1) * 64 + cc);
        float4 w2 = *reinterpret_cast<const float4*>(W + (kk + 2) * 64 + cc);
        float4 w3 = *reinterpret_cast<const float4*>(W + (kk + 3) * 64 + cc);
        #pragma unroll
        for (int n = 0; n < 32; n++) {
            float4 xv = *reinterpret_cast<const float4*>(Xw + n * 128 + kk);
            acc[n][0] += xv.x * w0.x + xv.y * w1.x + xv.z * w2.x + xv.w * w3.x;
            acc[n][1] += xv.x * w0.y + xv.y * w1.y + xv.z * w2.y + xv.w * w3.y;
            acc[n][2] += xv.x * w0.z + xv.y * w1.z + xv.z * w2.z + xv.w * w3.z;
            acc[n][3] += xv.x * w0.w + xv.y * w1.w + xv.z * w2.w + xv.w * w3.w;
        }
    }

    float4 bias = *reinterpret_cast<const float4*>(B + cc);
    #pragma unroll
    for (int n = 0; n < 32; n++) {
        int node = base + wave * 32 + n;
        if (node < N) {
            float4 r = make_float4(acc[n][0] + bias.x, acc[n][1] + bias.y,
                                   acc[n][2] + bias.z, acc[n][3] + bias.w);
            *reinterpret_cast<float4*>(O + (size_t)node * 64 + cc) = r;
        }
    }
}

// Pass A: one wave per edge. lane = h*16+d over HD=64.
__global__ __launch_bounds__(256) void edge_a(
    const int* __restrict__ ei, const float* __restrict__ ea,
    const float* __restrict__ We,
    const float* __restrict__ q, const float* __restrict__ k,
    float* __restrict__ ex, float* __restrict__ denom, int E)
{
    __shared__ float WeL[16 * 64];  // 4 KiB
    const int tid = threadIdx.x;
    for (int i = tid; i < 16 * 64; i += 256) WeL[i] = We[i];
    __syncthreads();

    const int ed = blockIdx.x * 4 + (tid >> 6);
    if (ed >= E) return;
    const int lane = tid & 63;
    const int src = ei[ed];
    const int dst = ei[E + ed];

    // e_t = sum_j ea[ed][j] * We[j][lane]
    float eav = ea[(size_t)ed * 16 + (lane & 15)];
    float et = 0.f;
    #pragma unroll
    for (int j = 0; j < 16; j++)
        et += __shfl(eav, j) * WeL[j * 64 + lane];

    float kj = k[(size_t)src * 64 + lane] + et;
    float qi = q[(size_t)dst * 64 + lane];
    float p = qi * kj;
    // reduce over d (16 lanes per head)
    p += __shfl_xor(p, 8);
    p += __shfl_xor(p, 4);
    p += __shfl_xor(p, 2);
    p += __shfl_xor(p, 1);
    float e1 = expf(p * 0.25f);   // alpha = p / sqrt(D=16)

    if ((lane & 15) == 0) {
        int h = lane >> 4;
        ex[(size_t)ed * 4 + h] = e1;
        atomicAdd(&denom[(size_t)dst * 4 + h], e1);
    }
}

// Pass B: normalize + scatter messages.
__global__ __launch_bounds__(256) void edge_b(
    const int* __restrict__ ei, const float* __restrict__ ea,
    const float* __restrict__ We,
    const float* __restrict__ v, const float* __restrict__ ex,
    const float* __restrict__ denom,
    float* __restrict__ out, float* __restrict__ asm_out, int E)
{
    __shared__ float WeL[16 * 64];
    const int tid = threadIdx.x;
    for (int i = tid; i < 16 * 64; i += 256) WeL[i] = We[i];
    __syncthreads();

    const int ed = blockIdx.x * 4 + (tid >> 6);
    if (ed >= E) return;
    const int lane = tid & 63;
    const int src = ei[ed];
    const int dst = ei[E + ed];

    float eav = ea[(size_t)ed * 16 + (lane & 15)];
    float et = 0.f;
    #pragma unroll
    for (int j = 0; j < 16; j++)
        et += __shfl(eav, j) * WeL[j * 64 + lane];

    float vj = v[(size_t)src * 64 + lane] + et;
    const int h = lane >> 4;
    float e1  = ex[(size_t)ed * 4 + h];
    float den = denom[(size_t)dst * 4 + h];
    float a   = e1 / (den + 1e-16f);

    if ((lane & 15) == 0)
        asm_out[(size_t)ed * 4 + h] = a;

    atomicAdd(&out[(size_t)dst * 64 + lane], a * vj);
}

__global__ __launch_bounds__(256) void copy_ei(
    const int* __restrict__ ei, float* __restrict__ o, int n2)
{
    int i = blockIdx.x * 256 + threadIdx.x;
    if (i < n2) o[i] = (float)ei[i];
}

extern "C" void kernel_launch(void* const* d_in, const int* in_sizes, int n_in,
                              void* d_out, int out_size, void* d_ws, size_t ws_size,
                              hipStream_t stream)
{
    const float* x   = (const float*)d_in[0];
    const int*   ei  = (const int*)  d_in[1];
    const float* ea  = (const float*)d_in[2];
    const float* Wq  = (const float*)d_in[3];
    const float* bq  = (const float*)d_in[4];
    const float* Wk  = (const float*)d_in[5];
    const float* bk  = (const float*)d_in[6];
    const float* Wv  = (const float*)d_in[7];
    const float* bv  = (const float*)d_in[8];
    const float* We  = (const float*)d_in[9];
    const float* Wsk = (const float*)d_in[10];
    const float* bsk = (const float*)d_in[11];

    const int N = in_sizes[0] / 128;
    const int E = in_sizes[1] / 2;

    // d_out: [ out (N*64) | edge_index as float (2E) | alpha_sm (E*4) ]
    float* out     = (float*)d_out;
    float* ei_out  = out + (size_t)N * 64;
    float* asm_out = ei_out + (size_t)2 * E;

    // ws: q | k | v | ex | denom   (~52 MB)
    float* q     = (float*)d_ws;
    float* k     = q + (size_t)N * 64;
    float* v     = k + (size_t)N * 64;
    float* ex    = v + (size_t)N * 64;
    float* denom = ex + (size_t)E * 4;

    hipMemsetAsync(denom, 0, (size_t)N * 4 * sizeof(float), stream);

    int nb1 = (N + 63) / 64;
    gemm_qkvs<<<nb1, 128, 0, stream>>>(x, Wq, bq, Wk, bk, Wv, bv, Wsk, bsk,
                                       q, k, v, out, N);

    int nb2 = (E + 3) / 4;
    edge_a<<<nb2, 256, 0, stream>>>(ei, ea, We, q, k, ex, denom, E);
    edge_b<<<nb2, 256, 0, stream>>>(ei, ea, We, v, ex, denom, out, asm_out, E);

    copy_ei<<<(2 * E + 255) / 256, 256, 0, stream>>>(ei, ei_out, 2 * E);
}

// Round 7
// 563.929 us; speedup vs baseline: 1.5526x; 1.5526x over previous
//
#include <hip/hip_runtime.h>

// GraphTransformer fused kernel set for MI355X (gfx950).
// N=50000, E=800000, IN=128, H=4, D=16, HD=64, ED=16.
//
// Pipeline (round 2 resubmit #5: single fused edge pass, deferred normalization):
//   memset denom=0 (ws), memset out-region of d_out = 0
//   K1 gemm_qkvs : q,k,v,skip = x@W+b into ws
//   K2 edge_fused: e1=exp(q[dst]·(k[src]+e)/4); raw e1 -> asm region of d_out;
//                  atomicAdd denom[dst,h] += e1; atomicAdd out[dst,:] += e1*(v[src]+e)
//   K3 fin_alpha : asm[i] /= (denom[dst,h]+1e-16)   (in place)
//   K4 fin_out   : out[i] = out[i]/(denom+1e-16) + skip[i]
//   K5 copy_ei   : edge_index -> d_out as float
//
// Softmax computed WITHOUT max-subtraction: exp(a)/sum(exp(a)) is the same
// ratio; |alpha| <~ 10 over this input distribution so fp32 exp is safe.

__global__ __launch_bounds__(128) void gemm_qkvs(
    const float* __restrict__ x,
    const float* __restrict__ Wq, const float* __restrict__ bq,
    const float* __restrict__ Wk, const float* __restrict__ bk,
    const float* __restrict__ Wv, const float* __restrict__ bv,
    const float* __restrict__ Wsk, const float* __restrict__ bsk,
    float* __restrict__ q, float* __restrict__ k, float* __restrict__ v,
    float* __restrict__ skip, int N)
{
    __shared__ float Xl[64 * 128];  // 32 KiB: 64 nodes x 128 features
    const int tid  = threadIdx.x;
    const int base = blockIdx.x * 64;
    const int nvalid = min(64, N - base);

    for (int i = tid; i < 64 * 32; i += 128) {
        int node = i >> 5;
        float4 val = make_float4(0.f, 0.f, 0.f, 0.f);
        if (node < nvalid)
            val = reinterpret_cast<const float4*>(x)[(size_t)(base + node) * 32 + (i & 31)];
        reinterpret_cast<float4*>(Xl)[i] = val;
    }
    __syncthreads();

    const int wave = tid >> 6;
    const int lane = tid & 63;
    const int c   = lane * 4;      // virtual col 0..255 over [q|k|v|skip]
    const int arr = c >> 6;
    const int cc  = c & 63;
    const float* W; const float* B; float* O;
    if (arr == 0)      { W = Wq;  B = bq;  O = q; }
    else if (arr == 1) { W = Wk;  B = bk;  O = k; }
    else if (arr == 2) { W = Wv;  B = bv;  O = v; }
    else               { W = Wsk; B = bsk; O = skip; }

    float acc[32][4];
    #pragma unroll
    for (int n = 0; n < 32; n++) {
        acc[n][0] = 0.f; acc[n][1] = 0.f; acc[n][2] = 0.f; acc[n][3] = 0.f;
    }

    const float* Xw = Xl + wave * 32 * 128;

    for (int kk = 0; kk < 128; kk += 4) {
        float4 w0 = *reinterpret_cast<const float4*>(W + (kk + 0) * 64 + cc);
        float4 w1 = *reinterpret_cast<const float4*>(W + (kk + 1) * 64 + cc);
        float4 w2 = *reinterpret_cast<const float4*>(W + (kk + 2) * 64 + cc);
        float4 w3 = *reinterpret_cast<const float4*>(W + (kk + 3) * 64 + cc);
        #pragma unroll
        for (int n = 0; n < 32; n++) {
            float4 xv = *reinterpret_cast<const float4*>(Xw + n * 128 + kk);
            acc[n][0] += xv.x * w0.x + xv.y * w1.x + xv.z * w2.x + xv.w * w3.x;
            acc[n][1] += xv.x * w0.y + xv.y * w1.y + xv.z * w2.y + xv.w * w3.y;
            acc[n][2] += xv.x * w0.z + xv.y * w1.z + xv.z * w2.z + xv.w * w3.z;
            acc[n][3] += xv.x * w0.w + xv.y * w1.w + xv.z * w2.w + xv.w * w3.w;
        }
    }

    float4 bias = *reinterpret_cast<const float4*>(B + cc);
    #pragma unroll
    for (int n = 0; n < 32; n++) {
        int node = base + wave * 32 + n;
        if (node < N) {
            float4 r = make_float4(acc[n][0] + bias.x, acc[n][1] + bias.y,
                                   acc[n][2] + bias.z, acc[n][3] + bias.w);
            *reinterpret_cast<float4*>(O + (size_t)node * 64 + cc) = r;
        }
    }
}

// Single fused edge pass. One wave per edge; lane = h*16+d.
__global__ __launch_bounds__(256) void edge_fused(
    const int* __restrict__ ei, const float* __restrict__ ea,
    const float* __restrict__ We,
    const float* __restrict__ q, const float* __restrict__ k,
    const float* __restrict__ v,
    float* __restrict__ exa,    // [E,4] raw exp(alpha) -> d_out asm region
    float* __restrict__ denom,  // [N,4]
    float* __restrict__ macc,   // [N,64] unnormalized message acc (d_out out region)
    int E)
{
    const int tid  = threadIdx.x;
    const int lane = tid & 63;

    // We column for this lane, in registers (16 coalesced loads, L2-cached)
    float WeR[16];
    #pragma unroll
    for (int j = 0; j < 16; j++) WeR[j] = We[j * 64 + lane];

    const int ed = blockIdx.x * 4 + (tid >> 6);
    if (ed >= E) return;

    const int src = ei[ed];
    const int dst = ei[E + ed];

    // each lane loads the full ea row (uniform address -> L1 broadcast)
    const float4* eap = reinterpret_cast<const float4*>(ea + (size_t)ed * 16);
    float4 a0 = eap[0], a1 = eap[1], a2 = eap[2], a3 = eap[3];
    float et = a0.x * WeR[0]  + a0.y * WeR[1]  + a0.z * WeR[2]  + a0.w * WeR[3]
             + a1.x * WeR[4]  + a1.y * WeR[5]  + a1.z * WeR[6]  + a1.w * WeR[7]
             + a2.x * WeR[8]  + a2.y * WeR[9]  + a2.z * WeR[10] + a2.w * WeR[11]
             + a3.x * WeR[12] + a3.y * WeR[13] + a3.z * WeR[14] + a3.w * WeR[15];

    const float kj = k[(size_t)src * 64 + lane] + et;
    const float vj = v[(size_t)src * 64 + lane] + et;
    const float qi = q[(size_t)dst * 64 + lane];

    float p = qi * kj;
    p += __shfl_xor(p, 8);
    p += __shfl_xor(p, 4);
    p += __shfl_xor(p, 2);
    p += __shfl_xor(p, 1);     // all 16 lanes of a head hold the dot

    const float e1 = __expf(p * 0.25f);   // alpha = p / sqrt(16)

    atomicAdd(&macc[(size_t)dst * 64 + lane], e1 * vj);

    if ((lane & 15) == 0) {
        const int h = lane >> 4;
        exa[(size_t)ed * 4 + h] = e1;
        atomicAdd(&denom[(size_t)dst * 4 + h], e1);
    }
}

// asm[i] /= denom[dst(e),h] + 1e-16, in place. i = e*4+h.
__global__ __launch_bounds__(256) void fin_alpha(
    const int* __restrict__ ei, const float* __restrict__ denom,
    float* __restrict__ asm_io, int E)
{
    int i = blockIdx.x * 256 + threadIdx.x;
    if (i >= E * 4) return;
    int e = i >> 2, h = i & 3;
    int dst = ei[E + e];
    asm_io[i] = asm_io[i] / (denom[dst * 4 + h] + 1e-16f);
}

// out[i] = macc[i]/(denom+1e-16) + skip[i]. i = node*64 + h*16 + d.
__global__ __launch_bounds__(256) void fin_out(
    const float* __restrict__ skip, const float* __restrict__ denom,
    float* __restrict__ out_io, int total)
{
    int i = blockIdx.x * 256 + threadIdx.x;
    if (i >= total) return;
    int node = i >> 6, h = (i & 63) >> 4;
    out_io[i] = out_io[i] / (denom[node * 4 + h] + 1e-16f) + skip[i];
}

__global__ __launch_bounds__(256) void copy_ei(
    const int* __restrict__ ei, float* __restrict__ o, int n2)
{
    int i = blockIdx.x * 256 + threadIdx.x;
    if (i < n2) o[i] = (float)ei[i];
}

extern "C" void kernel_launch(void* const* d_in, const int* in_sizes, int n_in,
                              void* d_out, int out_size, void* d_ws, size_t ws_size,
                              hipStream_t stream)
{
    const float* x   = (const float*)d_in[0];
    const int*   ei  = (const int*)  d_in[1];
    const float* ea  = (const float*)d_in[2];
    const float* Wq  = (const float*)d_in[3];
    const float* bq  = (const float*)d_in[4];
    const float* Wk  = (const float*)d_in[5];
    const float* bk  = (const float*)d_in[6];
    const float* Wv  = (const float*)d_in[7];
    const float* bv  = (const float*)d_in[8];
    const float* We  = (const float*)d_in[9];
    const float* Wsk = (const float*)d_in[10];
    const float* bsk = (const float*)d_in[11];

    const int N = in_sizes[0] / 128;
    const int E = in_sizes[1] / 2;

    // d_out: [ out (N*64) | edge_index as float (2E) | alpha_sm (E*4) ]
    float* out     = (float*)d_out;
    float* ei_out  = out + (size_t)N * 64;
    float* asm_out = ei_out + (size_t)2 * E;

    // ws: q | k | v | skip | denom   (52.0 MB)
    float* q     = (float*)d_ws;
    float* k     = q + (size_t)N * 64;
    float* v     = k + (size_t)N * 64;
    float* skip  = v + (size_t)N * 64;
    float* denom = skip + (size_t)N * 64;

    hipMemsetAsync(denom, 0, (size_t)N * 4 * sizeof(float), stream);
    hipMemsetAsync(out, 0, (size_t)N * 64 * sizeof(float), stream);

    int nb1 = (N + 63) / 64;
    gemm_qkvs<<<nb1, 128, 0, stream>>>(x, Wq, bq, Wk, bk, Wv, bv, Wsk, bsk,
                                       q, k, v, skip, N);

    int nb2 = (E + 3) / 4;
    edge_fused<<<nb2, 256, 0, stream>>>(ei, ea, We, q, k, v, asm_out, denom, out, E);

    fin_alpha<<<(E * 4 + 255) / 256, 256, 0, stream>>>(ei, denom, asm_out, E);
    fin_out<<<(N * 64 + 255) / 256, 256, 0, stream>>>(skip, denom, out, N * 64);
    copy_ei<<<(2 * E + 255) / 256, 256, 0, stream>>>(ei, ei_out, 2 * E);
}